// Round 1
// baseline (619.566 us; speedup 1.0000x reference)
//
#include <hip/hip_runtime.h>
#include <hip/hip_bf16.h>

// GraphConvNormRelu: y = einsum('bctu,puv,poc->botv', x, A*g, W) + sum_p b;
// train-mode BN over (B,T,V); relu; +x residual.
// B=32, C=64, T=512, V=54, P=4.
//
// Plan:
//   k_prep     : bf16 Wstack (p,o,c), bf16 At[v][p*54+u] (zero-padded 64x224),
//                bias sums, zero stat partial buffers (ws is poisoned each call).
//   k_pass1    : per block (b, 4 t's): U = Wstack @ X (MFMA, p=wave),
//                U' relayout via LDS, y = U' @ Astack (MFMA). Writes y_pre (fp32)
//                to d_out, accumulates per-channel sum/sumsq partials.
//   k_finalize : per-channel affine a,c from batch stats + gamma/beta.
//   k_pass2    : out = relu(a*y_pre + c) + x, float4, thread-local in-place.

typedef __bf16 bf16_t;
typedef __bf16 bf16x8 __attribute__((ext_vector_type(8)));
typedef float  f32x4  __attribute__((ext_vector_type(4)));

#define XT_STRIDE 72    // bf16 elems; 144 B rows, 16B-aligned for b128 reads
#define UP_STRIDE 232   // bf16 elems; 464 B rows, 16B-aligned

static __device__ __forceinline__ f32x4 mfma16(bf16x8 a, bf16x8 b, f32x4 c) {
  return __builtin_amdgcn_mfma_f32_16x16x32_bf16(a, b, c, 0, 0, 0);
}

// ---------------- k_prep ----------------
__global__ __launch_bounds__(256) void k_prep(
    const float* __restrict__ A, const float* __restrict__ g,
    const float* __restrict__ W, const float* __restrict__ bias,
    bf16_t* __restrict__ Wstk, bf16_t* __restrict__ At,
    float* __restrict__ bsum, float* __restrict__ stats) {
  int i = blockIdx.x * 256 + threadIdx.x;
  // Wstack[(p*64+o)*64 + c] = bf16(W)  (same flat layout as input W)
  if (i < 16384) Wstk[i] = (bf16_t)W[i];
  // At[v][pu] = bf16(A[p,u,v]*g[p,u,v]); rows padded to 64, cols to 224, zeros.
  if (i < 64 * 224) {
    int v = i / 224, pu = i - v * 224;
    float val = 0.f;
    if (v < 54 && pu < 216) { int idx = pu * 54 + v; val = A[idx] * g[idx]; }
    At[i] = (bf16_t)val;
  }
  if (i < 64) {
    float s = 0.f;
    for (int p = 0; p < 4; ++p) s += bias[p * 64 + i];
    bsum[i] = s;
  }
  if (i < 8192) stats[i] = 0.f;   // 64 buffers x (64 sum + 64 sumsq)
}

// ---------------- k_pass1 ----------------
__global__ __launch_bounds__(256) void k_pass1(
    const float* __restrict__ x, const bf16_t* __restrict__ Wstk,
    const bf16_t* __restrict__ At, const float* __restrict__ bsum,
    float* __restrict__ ypre, float* __restrict__ stats) {
  __shared__ bf16_t XtS[4 * 54 * XT_STRIDE];  // 31104 B : x tile, [tt][u][c]
  __shared__ bf16_t UpS[64 * UP_STRIDE];      // 29696 B : U'[o][p*54+u]

  const int tid  = threadIdx.x;
  const int bid  = blockIdx.x;
  const int b    = bid >> 7;          // / 128
  const int t0   = (bid & 127) << 2;  // * 4
  const int w    = tid >> 6;          // wave 0..3
  const int L    = tid & 63;
  const int quad = L >> 4;
  const int l15  = L & 15;

  // zero K-pad columns of U' (pu 216..223) — never rewritten
  for (int i = tid; i < 64 * 8; i += 256)
    UpS[(i >> 3) * UP_STRIDE + 216 + (i & 7)] = (bf16_t)0.0f;

  // stage x -> LDS bf16 [tt][u][c]; global reads coalesced along (t,u)
  const float* xb = x + (size_t)(b * 64 * 512 + t0) * 54;
  for (int j = tid; j < 64 * 216; j += 256) {
    int c = j / 216;
    int r = j - c * 216;
    float v = xb[(size_t)c * 27648 + r];
    int tt = r / 54;
    int u  = r - tt * 54;
    XtS[(tt * 54 + u) * XT_STRIDE + c] = (bf16_t)v;
  }

  // W fragments in registers: wave w owns p = w, m0 = 16*(4w+mi)
  bf16x8 wfr[4][2];
  #pragma unroll
  for (int mi = 0; mi < 4; ++mi) {
    const bf16_t* arow = Wstk + (((((w << 2) + mi) << 4) + l15) * 64) + (quad << 3);
    #pragma unroll
    for (int kk = 0; kk < 2; ++kk)
      wfr[mi][kk] = *(const bf16x8*)(arow + kk * 32);
  }

  const int obase = (w << 4) + (quad << 2);   // this thread's 4 output channels
  float bs[4];
  #pragma unroll
  for (int r = 0; r < 4; ++r) bs[r] = bsum[obase + r];

  bf16x8 zf;
  #pragma unroll
  for (int j = 0; j < 8; ++j) zf[j] = (bf16_t)0.0f;

  float ssum[4] = {0.f, 0.f, 0.f, 0.f};
  float ssq[4]  = {0.f, 0.f, 0.f, 0.f};

  __syncthreads();

  for (int tt = 0; tt < 4; ++tt) {
    // ---- step A: U[(p,o),u] = sum_c W[p,o,c] * X[c,u], p = w ----
    bf16x8 xfr[4][2];           // B-frags, shared across mi
    #pragma unroll
    for (int nt = 0; nt < 4; ++nt) {
      const int urow = (nt << 4) + l15;
      #pragma unroll
      for (int kk = 0; kk < 2; ++kk) {
        xfr[nt][kk] = zf;
        if (urow < 54)
          xfr[nt][kk] = *(const bf16x8*)(&XtS[(tt * 54 + urow) * XT_STRIDE + kk * 32 + (quad << 3)]);
      }
    }
    #pragma unroll
    for (int mi = 0; mi < 4; ++mi) {
      f32x4 acc[4];
      #pragma unroll
      for (int nt = 0; nt < 4; ++nt)
        #pragma unroll
        for (int e = 0; e < 4; ++e) acc[nt][e] = 0.f;
      #pragma unroll
      for (int kk = 0; kk < 2; ++kk)
        #pragma unroll
        for (int nt = 0; nt < 4; ++nt)
          acc[nt] = mfma16(wfr[mi][kk], xfr[nt][kk], acc[nt]);
      // write U' (C/D layout -> A-operand layout via LDS)
      #pragma unroll
      for (int nt = 0; nt < 4; ++nt) {
        const int u = (nt << 4) + l15;
        if (u < 54) {
          #pragma unroll
          for (int r = 0; r < 4; ++r) {
            int o = (mi << 4) + (quad << 2) + r;
            UpS[o * UP_STRIDE + w * 54 + u] = (bf16_t)acc[nt][r];
          }
        }
      }
    }
    __syncthreads();

    // ---- step B: y[o,v] = sum_pu U'[o,pu] * Astack[pu,v] ----
    bf16x8 afr[7];
    #pragma unroll
    for (int kk = 0; kk < 7; ++kk)
      afr[kk] = *(const bf16x8*)(&UpS[((w << 4) + l15) * UP_STRIDE + kk * 32 + (quad << 3)]);
    f32x4 acc[4];
    #pragma unroll
    for (int nt = 0; nt < 4; ++nt)
      #pragma unroll
      for (int e = 0; e < 4; ++e) acc[nt][e] = 0.f;
    #pragma unroll
    for (int kk = 0; kk < 7; ++kk) {
      #pragma unroll
      for (int nt = 0; nt < 4; ++nt) {
        bf16x8 bfr = *(const bf16x8*)(At + ((nt << 4) + l15) * 224 + kk * 32 + (quad << 3));
        acc[nt] = mfma16(afr[kk], bfr, acc[nt]);
      }
    }
    const int t = t0 + tt;
    #pragma unroll
    for (int nt = 0; nt < 4; ++nt) {
      const int vcol = (nt << 4) + l15;
      if (vcol < 54) {
        #pragma unroll
        for (int r = 0; r < 4; ++r) {
          float yv = acc[nt][r] + bs[r];
          ypre[(((size_t)b * 64 + (obase + r)) * 512 + t) * 54 + vcol] = yv;
          ssum[r] += yv;
          ssq[r]  += yv * yv;
        }
      }
    }
    __syncthreads();  // protect UpS before next tt overwrites it
  }

  // reduce stats over the 16 lanes of each quad-group (channels fixed per thread)
  #pragma unroll
  for (int off = 1; off < 16; off <<= 1) {
    #pragma unroll
    for (int r = 0; r < 4; ++r) {
      ssum[r] += __shfl_xor(ssum[r], off);
      ssq[r]  += __shfl_xor(ssq[r], off);
    }
  }
  if (l15 == 0) {
    float* sb = stats + (bid & 63) * 128;
    #pragma unroll
    for (int r = 0; r < 4; ++r) {
      atomicAdd(&sb[obase + r], ssum[r]);
      atomicAdd(&sb[64 + obase + r], ssq[r]);
    }
  }
}

// ---------------- k_finalize ----------------
__global__ void k_finalize(const float* __restrict__ gamma, const float* __restrict__ beta,
                           const float* __restrict__ stats, float* __restrict__ ac) {
  int o = threadIdx.x;
  if (o >= 64) return;
  float S = 0.f, Q = 0.f;
  for (int buf = 0; buf < 64; ++buf) {
    S += stats[buf * 128 + o];
    Q += stats[buf * 128 + 64 + o];
  }
  const float inv = 1.0f / 884736.0f;   // B*T*V
  float mean = S * inv;
  float var  = Q * inv - mean * mean;
  float a = gamma[o] * rsqrtf(var + 1e-5f);
  ac[o]      = a;
  ac[64 + o] = beta[o] - mean * a;
}

// ---------------- k_pass2 ----------------
__global__ __launch_bounds__(256) void k_pass2(const float* __restrict__ x,
                                               const float* __restrict__ ac,
                                               float* __restrict__ out) {
  size_t i4 = (size_t)blockIdx.x * 256 + threadIdx.x;
  int o = (int)((i4 / 6912) & 63);      // channel = (elem / (T*V)) % 64, T*V=27648
  float a = ac[o], c = ac[64 + o];
  float4 yp = ((const float4*)out)[i4];
  float4 xv = ((const float4*)x)[i4];
  float4 res;
  res.x = fmaxf(a * yp.x + c, 0.f) + xv.x;
  res.y = fmaxf(a * yp.y + c, 0.f) + xv.y;
  res.z = fmaxf(a * yp.z + c, 0.f) + xv.z;
  res.w = fmaxf(a * yp.w + c, 0.f) + xv.w;
  ((float4*)out)[i4] = res;
}

extern "C" void kernel_launch(void* const* d_in, const int* in_sizes, int n_in,
                              void* d_out, int out_size, void* d_ws, size_t ws_size,
                              hipStream_t stream) {
  const float* x     = (const float*)d_in[0];
  const float* A     = (const float*)d_in[1];
  const float* g     = (const float*)d_in[2];
  const float* W     = (const float*)d_in[3];
  const float* bias  = (const float*)d_in[4];
  const float* gamma = (const float*)d_in[5];
  const float* beta  = (const float*)d_in[6];

  char* ws = (char*)d_ws;
  bf16_t* Wstk = (bf16_t*)(ws + 0);        // 16384 bf16 = 32768 B
  bf16_t* At   = (bf16_t*)(ws + 32768);    // 64*224 bf16 = 28672 B
  float*  bsum = (float*)(ws + 61440);     // 64 f
  float*  stats= (float*)(ws + 61696);     // 8192 f
  float*  ac   = (float*)(ws + 94464);     // 128 f
  float*  out  = (float*)d_out;

  k_prep<<<64, 256, 0, stream>>>(A, g, W, bias, Wstk, At, bsum, stats);
  k_pass1<<<4096, 256, 0, stream>>>(x, Wstk, At, bsum, out, stats);
  k_finalize<<<1, 64, 0, stream>>>(gamma, beta, stats, ac);
  k_pass2<<<55296, 256, 0, stream>>>(x, ac, out);
}

// Round 2
// 610.349 us; speedup vs baseline: 1.0151x; 1.0151x over previous
//
#include <hip/hip_runtime.h>
#include <hip/hip_bf16.h>

// GraphConvNormRelu: y = einsum('bctu,puv,poc->botv', x, A*g, W) + sum_p b;
// train-mode BN over (B,T,V); relu; +x residual.  B=32, C=64, T=512, V=54, P=4.
//
// R2 structure:
//   k_prep  : bf16 Wstk [p][o][c], bf16 At [v(64)][pu(224)] zero-padded, bias sums,
//             zero stat buffers.
//   k_tr    : x fp32 [b][c][r=t*54+u] -> xT bf16 [b][r][c]  (conflict-free LDS tile)
//   k_pass1 : per block (b, 4 t):
//             step A: D[u][o] = X[u][c] @ W^T  (A-frags straight from global xT,
//                     W B-frags in registers, wave w = part p). Packed-dword U'
//                     scatter to LDS (consecutive-u lanes). Double-buffered U',
//                     ONE barrier per t.
//             step B: D[v][o] = At[v][pu] @ U'^T. Packed ypre stores (bf16 or f32),
//                     per-thread single-channel stats -> bucketed atomics.
//   k_finalize, k_pass2 (2-D grid, no div).

typedef __bf16 bf16_t;
typedef __bf16 bf16x8 __attribute__((ext_vector_type(8)));
typedef __bf16 bf16x4 __attribute__((ext_vector_type(4)));
typedef float  f32x4  __attribute__((ext_vector_type(4)));
typedef unsigned int uint32;

static __device__ __forceinline__ f32x4 mfma16(bf16x8 a, bf16x8 b, f32x4 c) {
  return __builtin_amdgcn_mfma_f32_16x16x32_bf16(a, b, c, 0, 0, 0);
}
static __device__ __forceinline__ uint32 pk2(float a, float b) {
  union { __bf16 h; unsigned short u; } ua, ub;
  ua.h = (__bf16)a; ub.h = (__bf16)b;
  return (uint32)ua.u | ((uint32)ub.u << 16);
}

// ---------------- k_prep ----------------
__global__ __launch_bounds__(256) void k_prep(
    const float* __restrict__ A, const float* __restrict__ g,
    const float* __restrict__ W, const float* __restrict__ bias,
    bf16_t* __restrict__ Wstk, bf16_t* __restrict__ At,
    float* __restrict__ bsum, float* __restrict__ stats) {
  int i = blockIdx.x * 256 + threadIdx.x;
  if (i < 16384) Wstk[i] = (bf16_t)W[i];
  if (i < 64 * 224) {
    int v = i / 224, pu = i - v * 224;
    float val = 0.f;
    if (v < 54 && pu < 216) { int idx = pu * 54 + v; val = A[idx] * g[idx]; }
    At[i] = (bf16_t)val;
  }
  if (i < 64) {
    float s = 0.f;
    for (int p = 0; p < 4; ++p) s += bias[p * 64 + i];
    bsum[i] = s;
  }
  if (i < 8192) stats[i] = 0.f;
}

// ---------------- k_tr : x[c][r] fp32 -> xT[r][c] bf16 ----------------
__global__ __launch_bounds__(256) void k_tr(const float* __restrict__ x,
                                            bf16_t* __restrict__ xT) {
  __shared__ bf16_t T[256 * 66];   // stride 66 bf16 = 33 dwords (odd -> 2-way max)
  const int tid = threadIdx.x;
  const int b = blockIdx.x / 108;
  const int rblk = blockIdx.x - b * 108;
  const int r0 = rblk << 8;
  const float* xb = x + (size_t)b * 64 * 27648 + r0;
  // read: 16 j-iters x 4 k: element (c = idx>>6, r = (idx&63) + 64k), coalesced
  #pragma unroll 4
  for (int j = 0; j < 16; ++j) {
    int idx = tid + (j << 8);
    int c = idx >> 6, r4 = idx & 63;
    const float* src = xb + (size_t)c * 27648 + r4;
    #pragma unroll
    for (int k = 0; k < 4; ++k) {
      float v = src[k << 6];
      T[(r4 + (k << 6)) * 66 + c] = (bf16_t)v;   // bank (r4 + c/2)%32 : 2-way
    }
  }
  __syncthreads();
  bf16_t* outb = xT + (((size_t)b * 27648 + r0) << 6);
  const uint32* Td = (const uint32*)T;
  #pragma unroll
  for (int j = 0; j < 8; ++j) {
    int row = (tid >> 3) + (j << 5);
    int seg = tid & 7;
    uint32 d0 = Td[row * 33 + (seg << 2) + 0];
    uint32 d1 = Td[row * 33 + (seg << 2) + 1];
    uint32 d2 = Td[row * 33 + (seg << 2) + 2];
    uint32 d3 = Td[row * 33 + (seg << 2) + 3];
    uint4 vv = make_uint4(d0, d1, d2, d3);
    *(uint4*)(outb + ((size_t)row << 6) + (seg << 3)) = vv;   // coalesced 16B
  }
}

// ---------------- k_pass1 ----------------
#define UPS 232   // U' row stride in bf16 (464 B, 16B-aligned)

template<bool YBF16>
__global__ __launch_bounds__(256) void k_pass1(
    const bf16_t* __restrict__ xT, const bf16_t* __restrict__ Wstk,
    const bf16_t* __restrict__ At, const float* __restrict__ bsum,
    void* __restrict__ yprev, float* __restrict__ stats) {
  __shared__ bf16_t UpS[2][64 * UPS];   // 59392 B double-buffered

  const int tid  = threadIdx.x;
  const int bid  = blockIdx.x;
  const int b    = bid >> 7;
  const int t0   = (bid & 127) << 2;
  const int w    = tid >> 6;
  const int L    = tid & 63;
  const int quad = L >> 4;
  const int l15  = L & 15;

  // zero K-pad cols 216..231 of both buffers (dwords 108..115 of 116/row)
  for (int i = tid; i < 1024; i += 256) {
    int buf = i >> 9, row = (i >> 3) & 63, d = i & 7;
    ((uint32*)UpS[buf])[row * 116 + 108 + d] = 0u;
  }

  // W B-frags (p = w), held in registers for the whole kernel
  bf16x8 wb[4][2];
  #pragma unroll
  for (int ot = 0; ot < 4; ++ot)
    #pragma unroll
    for (int kk = 0; kk < 2; ++kk)
      wb[ot][kk] = *(const bf16x8*)(Wstk + (((w << 6) + (ot << 4) + l15) << 6)
                                          + (kk << 5) + (quad << 3));

  const int oc = (w << 4) + l15;        // this thread's step-B channel
  const float bsv = bsum[oc];
  float ssum = 0.f, ssq = 0.f;

  for (int tt = 0; tt < 4; ++tt) {
    bf16_t* Up = UpS[tt & 1];
    const int t = t0 + tt;

    // ---- step A: D[u][o] ----
    const bf16_t* xbase = xT + (((size_t)b * 27648 + (size_t)t * 54) << 6);
    bf16x8 xa[4][2];
    #pragma unroll
    for (int ut = 0; ut < 4; ++ut)
      #pragma unroll
      for (int kk = 0; kk < 2; ++kk)
        xa[ut][kk] = *(const bf16x8*)(xbase + (((ut << 4) + l15) << 6)
                                            + (kk << 5) + (quad << 3));
    #pragma unroll
    for (int ut = 0; ut < 4; ++ut) {
      const int u0 = (ut << 4) + (quad << 2);
      #pragma unroll
      for (int ot = 0; ot < 4; ++ot) {
        f32x4 acc = {0.f, 0.f, 0.f, 0.f};
        acc = mfma16(xa[ut][0], wb[ot][0], acc);
        acc = mfma16(xa[ut][1], wb[ot][1], acc);
        if (u0 < 54) {
          uint32* dst = (uint32*)(Up + ((ot << 4) + l15) * UPS + w * 54 + u0);
          dst[0] = pk2(acc[0], acc[1]);
          if (u0 + 3 < 54) dst[1] = pk2(acc[2], acc[3]);
        }
      }
    }
    __syncthreads();

    // ---- step B: D[v][o] = At @ U'^T ----
    bf16x8 ub[7];
    #pragma unroll
    for (int kk = 0; kk < 7; ++kk)
      ub[kk] = *(const bf16x8*)(Up + ((w << 4) + l15) * UPS + (kk << 5) + (quad << 3));

    const size_t obase = (((size_t)((b << 6) + oc) << 9) + (size_t)t) * 54;
    #pragma unroll
    for (int mi = 0; mi < 4; ++mi) {
      f32x4 acc = {0.f, 0.f, 0.f, 0.f};
      #pragma unroll
      for (int kk = 0; kk < 7; ++kk) {
        bf16x8 av = *(const bf16x8*)(At + ((mi << 4) + l15) * 224
                                        + (kk << 5) + (quad << 3));
        acc = mfma16(av, ub[kk], acc);
      }
      const int v0 = (mi << 4) + (quad << 2);
      if (v0 + 3 < 54) {
        float y0 = acc[0] + bsv, y1 = acc[1] + bsv, y2 = acc[2] + bsv, y3 = acc[3] + bsv;
        if (YBF16) {
          uint32* d = (uint32*)((bf16_t*)yprev + obase + v0);
          d[0] = pk2(y0, y1); d[1] = pk2(y2, y3);
        } else {
          float2* d = (float2*)((float*)yprev + obase + v0);
          d[0] = make_float2(y0, y1); d[1] = make_float2(y2, y3);
        }
        ssum += y0 + y1 + y2 + y3;
        ssq  += y0 * y0 + y1 * y1 + y2 * y2 + y3 * y3;
      } else if (v0 == 52) {
        float y0 = acc[0] + bsv, y1 = acc[1] + bsv;
        if (YBF16) {
          *(uint32*)((bf16_t*)yprev + obase + v0) = pk2(y0, y1);
        } else {
          *(float2*)((float*)yprev + obase + v0) = make_float2(y0, y1);
        }
        ssum += y0 + y1;
        ssq  += y0 * y0 + y1 * y1;
      }
    }
    __syncthreads();   // one barrier per tt (dbuf covers write/read overlap)
  }

  // reduce stats across the 4 quads holding the same channel
  ssum += __shfl_xor(ssum, 16); ssq += __shfl_xor(ssq, 16);
  ssum += __shfl_xor(ssum, 32); ssq += __shfl_xor(ssq, 32);
  if (L < 16) {
    float* sb = stats + (bid & 63) * 128;
    atomicAdd(&sb[oc], ssum);
    atomicAdd(&sb[64 + oc], ssq);
  }
}

// ---------------- legacy pass1 (fp32 ypre in d_out; used only if ws tiny) ----
#define XT_STRIDE 72
#define UP_STRIDE 232
__global__ __launch_bounds__(256) void k_pass1_legacy(
    const float* __restrict__ x, const bf16_t* __restrict__ Wstk,
    const bf16_t* __restrict__ At, const float* __restrict__ bsum,
    float* __restrict__ ypre, float* __restrict__ stats) {
  __shared__ bf16_t XtS[4 * 54 * XT_STRIDE];
  __shared__ bf16_t UpS[64 * UP_STRIDE];
  const int tid = threadIdx.x, bid = blockIdx.x;
  const int b = bid >> 7, t0 = (bid & 127) << 2;
  const int w = tid >> 6, L = tid & 63, quad = L >> 4, l15 = L & 15;
  for (int i = tid; i < 64 * 8; i += 256)
    UpS[(i >> 3) * UP_STRIDE + 216 + (i & 7)] = (bf16_t)0.0f;
  const float* xb = x + (size_t)(b * 64 * 512 + t0) * 54;
  for (int j = tid; j < 64 * 216; j += 256) {
    int c = j / 216, r = j - c * 216;
    float v = xb[(size_t)c * 27648 + r];
    int tt = r / 54, u = r - tt * 54;
    XtS[(tt * 54 + u) * XT_STRIDE + c] = (bf16_t)v;
  }
  bf16x8 wfr[4][2];
  #pragma unroll
  for (int mi = 0; mi < 4; ++mi) {
    const bf16_t* arow = Wstk + (((((w << 2) + mi) << 4) + l15) * 64) + (quad << 3);
    #pragma unroll
    for (int kk = 0; kk < 2; ++kk) wfr[mi][kk] = *(const bf16x8*)(arow + kk * 32);
  }
  const int obase = (w << 4) + (quad << 2);
  float bs[4];
  #pragma unroll
  for (int r = 0; r < 4; ++r) bs[r] = bsum[obase + r];
  bf16x8 zf;
  #pragma unroll
  for (int j = 0; j < 8; ++j) zf[j] = (bf16_t)0.0f;
  float ssum[4] = {0.f,0.f,0.f,0.f}, ssq[4] = {0.f,0.f,0.f,0.f};
  __syncthreads();
  for (int tt = 0; tt < 4; ++tt) {
    bf16x8 xfr[4][2];
    #pragma unroll
    for (int nt = 0; nt < 4; ++nt) {
      const int urow = (nt << 4) + l15;
      #pragma unroll
      for (int kk = 0; kk < 2; ++kk) {
        xfr[nt][kk] = zf;
        if (urow < 54)
          xfr[nt][kk] = *(const bf16x8*)(&XtS[(tt * 54 + urow) * XT_STRIDE + kk * 32 + (quad << 3)]);
      }
    }
    #pragma unroll
    for (int mi = 0; mi < 4; ++mi) {
      f32x4 acc[4];
      #pragma unroll
      for (int nt = 0; nt < 4; ++nt)
        #pragma unroll
        for (int e = 0; e < 4; ++e) acc[nt][e] = 0.f;
      #pragma unroll
      for (int kk = 0; kk < 2; ++kk)
        #pragma unroll
        for (int nt = 0; nt < 4; ++nt)
          acc[nt] = mfma16(wfr[mi][kk], xfr[nt][kk], acc[nt]);
      #pragma unroll
      for (int nt = 0; nt < 4; ++nt) {
        const int u = (nt << 4) + l15;
        if (u < 54)
          #pragma unroll
          for (int r = 0; r < 4; ++r) {
            int o = (mi << 4) + (quad << 2) + r;
            UpS[o * UP_STRIDE + w * 54 + u] = (bf16_t)acc[nt][r];
          }
      }
    }
    __syncthreads();
    bf16x8 afr[7];
    #pragma unroll
    for (int kk = 0; kk < 7; ++kk)
      afr[kk] = *(const bf16x8*)(&UpS[((w << 4) + l15) * UP_STRIDE + kk * 32 + (quad << 3)]);
    f32x4 acc[4];
    #pragma unroll
    for (int nt = 0; nt < 4; ++nt)
      #pragma unroll
      for (int e = 0; e < 4; ++e) acc[nt][e] = 0.f;
    #pragma unroll
    for (int kk = 0; kk < 7; ++kk)
      #pragma unroll
      for (int nt = 0; nt < 4; ++nt) {
        bf16x8 bfr = *(const bf16x8*)(At + ((nt << 4) + l15) * 224 + kk * 32 + (quad << 3));
        acc[nt] = mfma16(afr[kk], bfr, acc[nt]);
      }
    const int t = t0 + tt;
    #pragma unroll
    for (int nt = 0; nt < 4; ++nt) {
      const int vcol = (nt << 4) + l15;
      if (vcol < 54)
        #pragma unroll
        for (int r = 0; r < 4; ++r) {
          float yv = acc[nt][r] + bs[r];
          ypre[(((size_t)b * 64 + (obase + r)) * 512 + t) * 54 + vcol] = yv;
          ssum[r] += yv; ssq[r] += yv * yv;
        }
    }
    __syncthreads();
  }
  #pragma unroll
  for (int off = 1; off < 16; off <<= 1)
    #pragma unroll
    for (int r = 0; r < 4; ++r) {
      ssum[r] += __shfl_xor(ssum[r], off);
      ssq[r]  += __shfl_xor(ssq[r], off);
    }
  if (l15 == 0) {
    float* sb = stats + (bid & 63) * 128;
    #pragma unroll
    for (int r = 0; r < 4; ++r) {
      atomicAdd(&sb[obase + r], ssum[r]);
      atomicAdd(&sb[64 + obase + r], ssq[r]);
    }
  }
}

// ---------------- k_finalize ----------------
__global__ void k_finalize(const float* __restrict__ gamma, const float* __restrict__ beta,
                           const float* __restrict__ stats, float* __restrict__ ac) {
  int o = threadIdx.x;
  if (o >= 64) return;
  float S = 0.f, Q = 0.f;
  for (int buf = 0; buf < 64; ++buf) {
    S += stats[buf * 128 + o];
    Q += stats[buf * 128 + 64 + o];
  }
  const float inv = 1.0f / 884736.0f;
  float mean = S * inv;
  float var  = Q * inv - mean * mean;
  float a = gamma[o] * rsqrtf(var + 1e-5f);
  ac[o] = a;
  ac[64 + o] = beta[o] - mean * a;
}

// ---------------- k_pass2 ----------------
template<bool YBF16>
__global__ __launch_bounds__(256) void k_pass2(const float* __restrict__ x,
                                               const float* __restrict__ ac,
                                               const void* __restrict__ yprev,
                                               float* __restrict__ out) {
  const int slab = blockIdx.y;
  const int o = slab & 63;
  const size_t base = (size_t)slab * 27648 + (size_t)(((blockIdx.x << 8) + threadIdx.x) << 2);
  const float a = ac[o], c = ac[64 + o];
  float y0, y1, y2, y3;
  if (YBF16) {
    bf16x4 yp = *(const bf16x4*)((const bf16_t*)yprev + base);
    y0 = (float)yp[0]; y1 = (float)yp[1]; y2 = (float)yp[2]; y3 = (float)yp[3];
  } else {
    float4 yp = *(const float4*)((const float*)yprev + base);
    y0 = yp.x; y1 = yp.y; y2 = yp.z; y3 = yp.w;
  }
  float4 xv = *(const float4*)(x + base);
  float4 r;
  r.x = fmaxf(fmaf(a, y0, c), 0.f) + xv.x;
  r.y = fmaxf(fmaf(a, y1, c), 0.f) + xv.y;
  r.z = fmaxf(fmaf(a, y2, c), 0.f) + xv.z;
  r.w = fmaxf(fmaf(a, y3, c), 0.f) + xv.w;
  *(float4*)(out + base) = r;
}

extern "C" void kernel_launch(void* const* d_in, const int* in_sizes, int n_in,
                              void* d_out, int out_size, void* d_ws, size_t ws_size,
                              hipStream_t stream) {
  const float* x     = (const float*)d_in[0];
  const float* A     = (const float*)d_in[1];
  const float* g     = (const float*)d_in[2];
  const float* W     = (const float*)d_in[3];
  const float* bias  = (const float*)d_in[4];
  const float* gamma = (const float*)d_in[5];
  const float* beta  = (const float*)d_in[6];

  char* ws = (char*)d_ws;
  bf16_t* Wstk  = (bf16_t*)(ws + 0);       // 32768 B
  bf16_t* At    = (bf16_t*)(ws + 32768);   // 28672 B
  float*  bsum  = (float*)(ws + 61440);    // 256 B
  float*  stats = (float*)(ws + 61696);    // 32768 B
  float*  ac    = (float*)(ws + 94464);    // 512 B
  const size_t XT_OFF   = 98304;
  const size_t XT_BYTES = (size_t)32 * 27648 * 64 * 2;      // 113246208
  const size_t YP_OFF   = XT_OFF + XT_BYTES;                 // 113344512
  bf16_t* xT = (bf16_t*)(ws + XT_OFF);
  float*  out = (float*)d_out;

  const size_t need_primary = YP_OFF + XT_BYTES + 4096;
  const size_t need_fbA     = YP_OFF + 4096;

  k_prep<<<64, 256, 0, stream>>>(A, g, W, bias, Wstk, At, bsum, stats);

  if (ws_size >= need_primary) {
    bf16_t* ypre = (bf16_t*)(ws + YP_OFF);
    k_tr<<<3456, 256, 0, stream>>>(x, xT);
    k_pass1<true><<<4096, 256, 0, stream>>>(xT, Wstk, At, bsum, ypre, stats);
    k_finalize<<<1, 64, 0, stream>>>(gamma, beta, stats, ac);
    k_pass2<true><<<dim3(27, 2048), 256, 0, stream>>>(x, ac, ypre, out);
  } else if (ws_size >= need_fbA) {
    k_tr<<<3456, 256, 0, stream>>>(x, xT);
    k_pass1<false><<<4096, 256, 0, stream>>>(xT, Wstk, At, bsum, out, stats);
    k_finalize<<<1, 64, 0, stream>>>(gamma, beta, stats, ac);
    k_pass2<false><<<dim3(27, 2048), 256, 0, stream>>>(x, ac, out, out);
  } else {
    k_pass1_legacy<<<4096, 256, 0, stream>>>(x, Wstk, At, bsum, out, stats);
    k_finalize<<<1, 64, 0, stream>>>(gamma, beta, stats, ac);
    k_pass2<false><<<dim3(27, 2048), 256, 0, stream>>>(x, ac, out, out);
  }
}